// Round 1
// baseline (336.797 us; speedup 1.0000x reference)
//
#include <hip/hip_runtime.h>

#define IN_FEATS 128
#define OUT_FEATS 64

// Kernel 1: h[row][lane] = dot(feat[row], W[lane]) + b[lane]
// One wave per row; lane = output feature; W row held in VGPRs.
__global__ __launch_bounds__(256) void linear_kernel(
    const float* __restrict__ feat, const float* __restrict__ W,
    const float* __restrict__ b, float* __restrict__ h, int n_nodes)
{
    const int lane = threadIdx.x & 63;
    const int wave = threadIdx.x >> 6;

    // Load this lane's W row (out-feature = lane) into registers: 128 floats.
    float w[IN_FEATS];
    const float4* Wrow = (const float4*)(W + (size_t)lane * IN_FEATS);
#pragma unroll
    for (int i = 0; i < IN_FEATS / 4; ++i) {
        float4 t = Wrow[i];
        w[4*i+0] = t.x; w[4*i+1] = t.y; w[4*i+2] = t.z; w[4*i+3] = t.w;
    }
    const float bias = b[lane];

    const int stride = gridDim.x * 4;
    for (int row = blockIdx.x * 4 + wave; row < n_nodes; row += stride) {
        const float4* frow = (const float4*)(feat + (size_t)row * IN_FEATS);
        // 4 independent accumulator chains to hide FMA latency.
        float a0 = bias, a1 = 0.f, a2 = 0.f, a3 = 0.f;
#pragma unroll
        for (int k = 0; k < IN_FEATS / 4; ++k) {
            float4 f = frow[k];  // wave-uniform address -> one 16B request
            a0 += f.x * w[4*k+0];
            a1 += f.y * w[4*k+1];
            a2 += f.z * w[4*k+2];
            a3 += f.w * w[4*k+3];
        }
        h[(size_t)row * OUT_FEATS + lane] = (a0 + a1) + (a2 + a3);
    }
}

// Kernel 2: for each edge e: out[dst[e]][:] += h[src[e]][:] * ew[e]
// One wave per edge; lane = feature. Coalesced gather + contiguous atomics.
__global__ __launch_bounds__(256) void scatter_kernel(
    const float* __restrict__ h, const int* __restrict__ esrc,
    const int* __restrict__ edst, const float* __restrict__ ew,
    float* __restrict__ out, int n_edges)
{
    const int lane = threadIdx.x & 63;
    const int wave = threadIdx.x >> 6;
    const int stride = gridDim.x * 4;
    for (int e = blockIdx.x * 4 + wave; e < n_edges; e += stride) {
        const int s = esrc[e];
        const int d = edst[e];
        const float w = ew[e];
        const float v = h[(size_t)s * OUT_FEATS + lane] * w;
        atomicAdd(out + (size_t)d * OUT_FEATS + lane, v);
    }
}

extern "C" void kernel_launch(void* const* d_in, const int* in_sizes, int n_in,
                              void* d_out, int out_size, void* d_ws, size_t ws_size,
                              hipStream_t stream) {
    const float* feat = (const float*)d_in[0];
    const int*   esrc = (const int*)d_in[1];
    const int*   edst = (const int*)d_in[2];
    const float* ew   = (const float*)d_in[3];
    const float* W    = (const float*)d_in[4];
    const float* b    = (const float*)d_in[5];
    float* out = (float*)d_out;
    float* h   = (float*)d_ws;   // [n_nodes, 64] fp32 = 12.8 MB

    const int n_nodes = in_sizes[0] / IN_FEATS;  // 50000
    const int n_edges = in_sizes[1];             // 800000

    // Harness poisons d_out with 0xAA; atomics need zeros.
    hipMemsetAsync(d_out, 0, (size_t)out_size * sizeof(float), stream);

    linear_kernel<<<1024, 256, 0, stream>>>(feat, W, b, h, n_nodes);
    scatter_kernel<<<8192, 256, 0, stream>>>(h, esrc, edst, ew, out, n_edges);
}

// Round 2
// 312.363 us; speedup vs baseline: 1.0782x; 1.0782x over previous
//
#include <hip/hip_runtime.h>

#define IN_FEATS 128
#define OUT_FEATS 64
#define TM 64  // rows per linear block

__device__ inline void fma4(float4& a, float s, const float4& v) {
    a.x += s * v.x; a.y += s * v.y; a.z += s * v.z; a.w += s * v.w;
}

// ---------------- Linear: h = feat @ W^T + b ----------------
// Block: 256 threads -> 64 rows x 64 cols tile. Thread = 4 rows x 4 cols.
// LDS: feat tile 64x128 (32KB) + Wt[k][c] 128x64 (32KB) = 64KB.
__global__ __launch_bounds__(256) void linear_gemm(
    const float* __restrict__ feat, const float* __restrict__ W,
    const float* __restrict__ b, float* __restrict__ h, int n_nodes)
{
    __shared__ float fs[TM * IN_FEATS];           // [row][k]
    __shared__ float wt[IN_FEATS * OUT_FEATS];    // [k][col]
    const int tid  = threadIdx.x;
    const int row0 = blockIdx.x * TM;

    // Stage Wt (transpose of W). thread: col c = tid&63, k-range (tid>>6)*32.
    {
        const int c  = tid & 63;
        const int kb = (tid >> 6) * 32;
        const float4* wrow = (const float4*)(W + (size_t)c * IN_FEATS + kb);
#pragma unroll
        for (int i = 0; i < 8; ++i) {
            float4 t = wrow[i];
            int k = kb + i * 4;
            wt[(k + 0) * OUT_FEATS + c] = t.x;
            wt[(k + 1) * OUT_FEATS + c] = t.y;
            wt[(k + 2) * OUT_FEATS + c] = t.z;
            wt[(k + 3) * OUT_FEATS + c] = t.w;
        }
    }
    // Stage feat tile: 2048 float4, 256 threads x 8, fully coalesced.
    {
#pragma unroll
        for (int i = 0; i < 8; ++i) {
            int flat = i * 256 + tid;        // float4 index
            int r  = flat >> 5;              // 32 float4 per row
            int kc = flat & 31;
            int gr = row0 + r;
            float4 t = (gr < n_nodes)
                ? ((const float4*)(feat + (size_t)gr * IN_FEATS))[kc]
                : make_float4(0.f, 0.f, 0.f, 0.f);
            *((float4*)&fs[r * IN_FEATS + kc * 4]) = t;
        }
    }
    __syncthreads();

    const int tx = tid & 15;   // col group: cols tx*4 .. tx*4+3
    const int ty = tid >> 4;   // row group: rows ty*4 .. ty*4+3

    float4 acc[4];
#pragma unroll
    for (int i = 0; i < 4; ++i) acc[i] = make_float4(0.f, 0.f, 0.f, 0.f);

    for (int k = 0; k < IN_FEATS; k += 4) {
        float4 fv[4], wv[4];
#pragma unroll
        for (int i = 0; i < 4; ++i)
            fv[i] = *((const float4*)&fs[(ty * 4 + i) * IN_FEATS + k]);
#pragma unroll
        for (int j = 0; j < 4; ++j)
            wv[j] = *((const float4*)&wt[(k + j) * OUT_FEATS + tx * 4]);
#pragma unroll
        for (int i = 0; i < 4; ++i) {
            fma4(acc[i], fv[i].x, wv[0]);
            fma4(acc[i], fv[i].y, wv[1]);
            fma4(acc[i], fv[i].z, wv[2]);
            fma4(acc[i], fv[i].w, wv[3]);
        }
    }

    float4 b4 = ((const float4*)b)[tx];
#pragma unroll
    for (int i = 0; i < 4; ++i) {
        int r = row0 + ty * 4 + i;
        if (r < n_nodes) {
            float4 o = acc[i];
            o.x += b4.x; o.y += b4.y; o.z += b4.z; o.w += b4.w;
            ((float4*)(h + (size_t)r * OUT_FEATS))[tx] = o;
        }
    }
}

// ---------------- CSR build ----------------
__global__ __launch_bounds__(256) void hist_kernel(
    const int* __restrict__ edst, int* __restrict__ deg, int n_edges)
{
    int e = blockIdx.x * blockDim.x + threadIdx.x;
    if (e < n_edges) atomicAdd(&deg[edst[e]], 1);
}

// Single-block exclusive scan; writes offsets in place (deg->offsets),
// mirrors into cursor, writes total at deg[n].
__global__ __launch_bounds__(256) void scan_kernel(
    int* __restrict__ deg, int* __restrict__ cursor, int n)
{
    const int T = 16;            // elems per thread per chunk
    const int CHUNK = 256 * T;   // 4096
    __shared__ int wsum[4];
    __shared__ int wpre[4];
    __shared__ int ctot;
    const int tid  = threadIdx.x;
    const int lane = tid & 63;
    const int wv   = tid >> 6;
    int base = 0;
    const int nchunks = (n + CHUNK - 1) / CHUNK;
    for (int ch = 0; ch < nchunks; ++ch) {
        int i0 = ch * CHUNK + tid * T;
        int v[T];
        int s = 0;
#pragma unroll
        for (int j = 0; j < T; ++j) {
            int idx = i0 + j;
            v[j] = (idx < n) ? deg[idx] : 0;
        }
#pragma unroll
        for (int j = 0; j < T; ++j) { int t = v[j]; v[j] = s; s += t; }
        // wave-level inclusive scan of per-thread sums
        int inc = s;
        for (int off = 1; off < 64; off <<= 1) {
            int t = __shfl_up(inc, off, 64);
            if (lane >= off) inc += t;
        }
        int wexcl = inc - s;
        if (lane == 63) wsum[wv] = inc;
        __syncthreads();
        if (tid == 0) {
            int a = 0;
            for (int k = 0; k < 4; ++k) { wpre[k] = a; a += wsum[k]; }
            ctot = a;
        }
        __syncthreads();
        int tbase = base + wpre[wv] + wexcl;
#pragma unroll
        for (int j = 0; j < T; ++j) {
            int idx = i0 + j;
            if (idx < n) {
                int e = tbase + v[j];
                deg[idx] = e;
                cursor[idx] = e;
            }
        }
        base += ctot;
        __syncthreads();
    }
    if (tid == 0) deg[n] = base;
}

__global__ __launch_bounds__(256) void fill_kernel(
    const int* __restrict__ esrc, const int* __restrict__ edst,
    const float* __restrict__ ew, int* __restrict__ cursor,
    int2* __restrict__ perm2, int n_edges)
{
    int e = blockIdx.x * blockDim.x + threadIdx.x;
    if (e < n_edges) {
        int d = edst[e];
        int pos = atomicAdd(&cursor[d], 1);
        perm2[pos] = make_int2(esrc[e], __float_as_int(ew[e]));
    }
}

// One wave per dst node; lane = output feature. No atomics.
__global__ __launch_bounds__(256) void gather_kernel(
    const float* __restrict__ h, const int* __restrict__ offsets,
    const int2* __restrict__ perm2, float* __restrict__ out, int n_nodes)
{
    int wave = (blockIdx.x * blockDim.x + threadIdx.x) >> 6;
    int lane = threadIdx.x & 63;
    if (wave >= n_nodes) return;
    int s0 = offsets[wave], s1 = offsets[wave + 1];
    float acc = 0.f;
    int idx = s0;
    for (; idx + 1 < s1; idx += 2) {
        int2 m0 = perm2[idx];
        int2 m1 = perm2[idx + 1];
        float h0 = h[(size_t)m0.x * OUT_FEATS + lane];
        float h1 = h[(size_t)m1.x * OUT_FEATS + lane];
        acc += h0 * __int_as_float(m0.y);
        acc += h1 * __int_as_float(m1.y);
    }
    if (idx < s1) {
        int2 m = perm2[idx];
        acc += h[(size_t)m.x * OUT_FEATS + lane] * __int_as_float(m.y);
    }
    out[(size_t)wave * OUT_FEATS + lane] = acc;
}

// Fallback atomic scatter (used only if ws too small for CSR).
__global__ __launch_bounds__(256) void scatter_kernel(
    const float* __restrict__ h, const int* __restrict__ esrc,
    const int* __restrict__ edst, const float* __restrict__ ew,
    float* __restrict__ out, int n_edges)
{
    const int lane = threadIdx.x & 63;
    const int wave = threadIdx.x >> 6;
    const int stride = gridDim.x * 4;
    for (int e = blockIdx.x * 4 + wave; e < n_edges; e += stride) {
        const int s = esrc[e];
        const int d = edst[e];
        const float w = ew[e];
        atomicAdd(out + (size_t)d * OUT_FEATS + lane,
                  h[(size_t)s * OUT_FEATS + lane] * w);
    }
}

extern "C" void kernel_launch(void* const* d_in, const int* in_sizes, int n_in,
                              void* d_out, int out_size, void* d_ws, size_t ws_size,
                              hipStream_t stream) {
    const float* feat = (const float*)d_in[0];
    const int*   esrc = (const int*)d_in[1];
    const int*   edst = (const int*)d_in[2];
    const float* ew   = (const float*)d_in[3];
    const float* W    = (const float*)d_in[4];
    const float* b    = (const float*)d_in[5];
    float* out = (float*)d_out;

    const int n_nodes = in_sizes[0] / IN_FEATS;  // 50000
    const int n_edges = in_sizes[1];             // 800000

    // ws layout: h | offsets(n+1) | cursor(n) | perm2(E int2)
    char* wsb = (char*)d_ws;
    float* h = (float*)wsb;
    size_t off_offsets = (size_t)n_nodes * OUT_FEATS * sizeof(float);
    size_t sz_offsets  = (((size_t)(n_nodes + 1) * sizeof(int)) + 15) & ~(size_t)15;
    size_t off_cursor  = off_offsets + sz_offsets;
    size_t sz_cursor   = (((size_t)n_nodes * sizeof(int)) + 15) & ~(size_t)15;
    size_t off_perm    = off_cursor + sz_cursor;
    size_t needed      = off_perm + (size_t)n_edges * sizeof(int2);

    linear_gemm<<<(n_nodes + TM - 1) / TM, 256, 0, stream>>>(feat, W, b, h, n_nodes);

    if (ws_size >= needed) {
        int*  offsets = (int*)(wsb + off_offsets);
        int*  cursor  = (int*)(wsb + off_cursor);
        int2* perm2   = (int2*)(wsb + off_perm);
        hipMemsetAsync(offsets, 0, (size_t)(n_nodes + 1) * sizeof(int), stream);
        hist_kernel<<<(n_edges + 255) / 256, 256, 0, stream>>>(edst, offsets, n_edges);
        scan_kernel<<<1, 256, 0, stream>>>(offsets, cursor, n_nodes);
        fill_kernel<<<(n_edges + 255) / 256, 256, 0, stream>>>(esrc, edst, ew, cursor, perm2, n_edges);
        gather_kernel<<<((size_t)n_nodes * 64 + 255) / 256, 256, 0, stream>>>(h, offsets, perm2, out, n_nodes);
    } else {
        hipMemsetAsync(d_out, 0, (size_t)out_size * sizeof(float), stream);
        scatter_kernel<<<8192, 256, 0, stream>>>(h, esrc, edst, ew, out, n_edges);
    }
}

// Round 3
// 238.645 us; speedup vs baseline: 1.4113x; 1.3089x over previous
//
#include <hip/hip_runtime.h>

#define IN_FEATS 128
#define OUT_FEATS 64
#define TM 64          // rows per linear block
#define SCAN_CHUNK 1024  // elems per scan block (256 threads x 4)

__device__ inline void fma4(float4& a, float s, const float4& v) {
    a.x += s * v.x; a.y += s * v.y; a.z += s * v.z; a.w += s * v.w;
}

// ---------------- Linear: h = feat @ W^T + b ----------------
__global__ __launch_bounds__(256) void linear_gemm(
    const float* __restrict__ feat, const float* __restrict__ W,
    const float* __restrict__ b, float* __restrict__ h, int n_nodes)
{
    __shared__ float fs[TM * IN_FEATS];           // [row][k]
    __shared__ float wt[IN_FEATS * OUT_FEATS];    // [k][col]
    const int tid  = threadIdx.x;
    const int row0 = blockIdx.x * TM;

    {
        const int c  = tid & 63;
        const int kb = (tid >> 6) * 32;
        const float4* wrow = (const float4*)(W + (size_t)c * IN_FEATS + kb);
#pragma unroll
        for (int i = 0; i < 8; ++i) {
            float4 t = wrow[i];
            int k = kb + i * 4;
            wt[(k + 0) * OUT_FEATS + c] = t.x;
            wt[(k + 1) * OUT_FEATS + c] = t.y;
            wt[(k + 2) * OUT_FEATS + c] = t.z;
            wt[(k + 3) * OUT_FEATS + c] = t.w;
        }
    }
    {
#pragma unroll
        for (int i = 0; i < 8; ++i) {
            int flat = i * 256 + tid;
            int r  = flat >> 5;
            int kc = flat & 31;
            int gr = row0 + r;
            float4 t = (gr < n_nodes)
                ? ((const float4*)(feat + (size_t)gr * IN_FEATS))[kc]
                : make_float4(0.f, 0.f, 0.f, 0.f);
            *((float4*)&fs[r * IN_FEATS + kc * 4]) = t;
        }
    }
    __syncthreads();

    const int tx = tid & 15;
    const int ty = tid >> 4;

    float4 acc[4];
#pragma unroll
    for (int i = 0; i < 4; ++i) acc[i] = make_float4(0.f, 0.f, 0.f, 0.f);

    for (int k = 0; k < IN_FEATS; k += 4) {
        float4 fv[4], wv[4];
#pragma unroll
        for (int i = 0; i < 4; ++i)
            fv[i] = *((const float4*)&fs[(ty * 4 + i) * IN_FEATS + k]);
#pragma unroll
        for (int j = 0; j < 4; ++j)
            wv[j] = *((const float4*)&wt[(k + j) * OUT_FEATS + tx * 4]);
#pragma unroll
        for (int i = 0; i < 4; ++i) {
            fma4(acc[i], fv[i].x, wv[0]);
            fma4(acc[i], fv[i].y, wv[1]);
            fma4(acc[i], fv[i].z, wv[2]);
            fma4(acc[i], fv[i].w, wv[3]);
        }
    }

    float4 b4 = ((const float4*)b)[tx];
#pragma unroll
    for (int i = 0; i < 4; ++i) {
        int r = row0 + ty * 4 + i;
        if (r < n_nodes) {
            float4 o = acc[i];
            o.x += b4.x; o.y += b4.y; o.z += b4.z; o.w += b4.w;
            ((float4*)(h + (size_t)r * OUT_FEATS))[tx] = o;
        }
    }
}

// ---------------- CSR build ----------------
__global__ __launch_bounds__(256) void hist_kernel(
    const int* __restrict__ edst, int* __restrict__ deg, int n_edges)
{
    int e = blockIdx.x * blockDim.x + threadIdx.x;
    if (e < n_edges) atomicAdd(&deg[edst[e]], 1);
}

// Phase 1: per-block reduce of SCAN_CHUNK elems -> partials[blk]
__global__ __launch_bounds__(256) void scan_p1(
    const int* __restrict__ deg, int* __restrict__ partials, int n)
{
    __shared__ int wsum[4];
    const int tid  = threadIdx.x;
    const int lane = tid & 63;
    const int wv   = tid >> 6;
    int i0 = blockIdx.x * SCAN_CHUNK + tid * 4;
    int s = 0;
#pragma unroll
    for (int j = 0; j < 4; ++j) {
        int idx = i0 + j;
        s += (idx < n) ? deg[idx] : 0;
    }
    for (int off = 32; off > 0; off >>= 1) s += __shfl_down(s, off, 64);
    if (lane == 0) wsum[wv] = s;
    __syncthreads();
    if (tid == 0) partials[blockIdx.x] = wsum[0] + wsum[1] + wsum[2] + wsum[3];
}

// Phase 2: single-wave exclusive scan of nb partials; total at partials[nb]
__global__ __launch_bounds__(64) void scan_p2(int* __restrict__ partials, int nb)
{
    int lane = threadIdx.x;
    int v = (lane < nb) ? partials[lane] : 0;
    int inc = v;
    for (int off = 1; off < 64; off <<= 1) {
        int t = __shfl_up(inc, off, 64);
        if (lane >= off) inc += t;
    }
    int excl = inc - v;
    if (lane < nb) partials[lane] = excl;
    if (lane == 63) partials[nb] = inc;  // grand total
}

// Phase 3: local scan + base -> offsets & cursor; offsets[n] = total
__global__ __launch_bounds__(256) void scan_p3(
    int* __restrict__ deg, int* __restrict__ cursor,
    const int* __restrict__ partials, int n, int nb)
{
    __shared__ int wsum[4];
    __shared__ int wpre[4];
    const int tid  = threadIdx.x;
    const int lane = tid & 63;
    const int wv   = tid >> 6;
    int i0 = blockIdx.x * SCAN_CHUNK + tid * 4;
    int v[4];
    int s = 0;
#pragma unroll
    for (int j = 0; j < 4; ++j) {
        int idx = i0 + j;
        v[j] = (idx < n) ? deg[idx] : 0;
    }
#pragma unroll
    for (int j = 0; j < 4; ++j) { int t = v[j]; v[j] = s; s += t; }
    int inc = s;
    for (int off = 1; off < 64; off <<= 1) {
        int t = __shfl_up(inc, off, 64);
        if (lane >= off) inc += t;
    }
    int wexcl = inc - s;
    if (lane == 63) wsum[wv] = inc;
    __syncthreads();
    if (tid == 0) {
        int a = 0;
        for (int k = 0; k < 4; ++k) { wpre[k] = a; a += wsum[k]; }
    }
    __syncthreads();
    int tbase = partials[blockIdx.x] + wpre[wv] + wexcl;
#pragma unroll
    for (int j = 0; j < 4; ++j) {
        int idx = i0 + j;
        if (idx < n) {
            int e = tbase + v[j];
            deg[idx] = e;
            cursor[idx] = e;
        }
    }
    if (blockIdx.x == 0 && tid == 0) deg[n] = partials[nb];
}

__global__ __launch_bounds__(256) void fill_kernel(
    const int* __restrict__ esrc, const int* __restrict__ edst,
    const float* __restrict__ ew, int* __restrict__ cursor,
    int2* __restrict__ perm2, int n_edges)
{
    int e = blockIdx.x * blockDim.x + threadIdx.x;
    if (e < n_edges) {
        int d = edst[e];
        int pos = atomicAdd(&cursor[d], 1);
        perm2[pos] = make_int2(esrc[e], __float_as_int(ew[e]));
    }
}

// One wave per dst node; lane = output feature. No atomics.
__global__ __launch_bounds__(256) void gather_kernel(
    const float* __restrict__ h, const int* __restrict__ offsets,
    const int2* __restrict__ perm2, float* __restrict__ out, int n_nodes)
{
    int wave = (blockIdx.x * blockDim.x + threadIdx.x) >> 6;
    int lane = threadIdx.x & 63;
    if (wave >= n_nodes) return;
    int s0 = offsets[wave], s1 = offsets[wave + 1];
    float acc = 0.f;
    int idx = s0;
    for (; idx + 3 < s1; idx += 4) {
        int2 m0 = perm2[idx];
        int2 m1 = perm2[idx + 1];
        int2 m2 = perm2[idx + 2];
        int2 m3 = perm2[idx + 3];
        float h0 = h[(size_t)m0.x * OUT_FEATS + lane];
        float h1 = h[(size_t)m1.x * OUT_FEATS + lane];
        float h2 = h[(size_t)m2.x * OUT_FEATS + lane];
        float h3 = h[(size_t)m3.x * OUT_FEATS + lane];
        acc += h0 * __int_as_float(m0.y);
        acc += h1 * __int_as_float(m1.y);
        acc += h2 * __int_as_float(m2.y);
        acc += h3 * __int_as_float(m3.y);
    }
    for (; idx < s1; ++idx) {
        int2 m = perm2[idx];
        acc += h[(size_t)m.x * OUT_FEATS + lane] * __int_as_float(m.y);
    }
    out[(size_t)wave * OUT_FEATS + lane] = acc;
}

// Fallback atomic scatter (used only if ws too small for CSR).
__global__ __launch_bounds__(256) void scatter_kernel(
    const float* __restrict__ h, const int* __restrict__ esrc,
    const int* __restrict__ edst, const float* __restrict__ ew,
    float* __restrict__ out, int n_edges)
{
    const int lane = threadIdx.x & 63;
    const int wave = threadIdx.x >> 6;
    const int stride = gridDim.x * 4;
    for (int e = blockIdx.x * 4 + wave; e < n_edges; e += stride) {
        const int s = esrc[e];
        const int d = edst[e];
        const float w = ew[e];
        atomicAdd(out + (size_t)d * OUT_FEATS + lane,
                  h[(size_t)s * OUT_FEATS + lane] * w);
    }
}

extern "C" void kernel_launch(void* const* d_in, const int* in_sizes, int n_in,
                              void* d_out, int out_size, void* d_ws, size_t ws_size,
                              hipStream_t stream) {
    const float* feat = (const float*)d_in[0];
    const int*   esrc = (const int*)d_in[1];
    const int*   edst = (const int*)d_in[2];
    const float* ew   = (const float*)d_in[3];
    const float* W    = (const float*)d_in[4];
    const float* b    = (const float*)d_in[5];
    float* out = (float*)d_out;

    const int n_nodes = in_sizes[0] / IN_FEATS;  // 50000
    const int n_edges = in_sizes[1];             // 800000
    const int nb = (n_nodes + SCAN_CHUNK - 1) / SCAN_CHUNK;  // 49

    // ws layout: h | offsets(n+1) | cursor(n) | partials(nb+1) | perm2(E int2)
    char* wsb = (char*)d_ws;
    float* h = (float*)wsb;
    size_t off_offsets = (size_t)n_nodes * OUT_FEATS * sizeof(float);
    size_t sz_offsets  = (((size_t)(n_nodes + 1) * sizeof(int)) + 15) & ~(size_t)15;
    size_t off_cursor  = off_offsets + sz_offsets;
    size_t sz_cursor   = (((size_t)n_nodes * sizeof(int)) + 15) & ~(size_t)15;
    size_t off_part    = off_cursor + sz_cursor;
    size_t sz_part     = (((size_t)(nb + 1) * sizeof(int)) + 15) & ~(size_t)15;
    size_t off_perm    = off_part + sz_part;
    size_t needed      = off_perm + (size_t)n_edges * sizeof(int2);

    linear_gemm<<<(n_nodes + TM - 1) / TM, 256, 0, stream>>>(feat, W, b, h, n_nodes);

    if (ws_size >= needed) {
        int*  offsets  = (int*)(wsb + off_offsets);
        int*  cursor   = (int*)(wsb + off_cursor);
        int*  partials = (int*)(wsb + off_part);
        int2* perm2    = (int2*)(wsb + off_perm);
        hipMemsetAsync(offsets, 0, (size_t)(n_nodes + 1) * sizeof(int), stream);
        hist_kernel<<<(n_edges + 255) / 256, 256, 0, stream>>>(edst, offsets, n_edges);
        scan_p1<<<nb, 256, 0, stream>>>(offsets, partials, n_nodes);
        scan_p2<<<1, 64, 0, stream>>>(partials, nb);
        scan_p3<<<nb, 256, 0, stream>>>(offsets, cursor, partials, n_nodes, nb);
        fill_kernel<<<(n_edges + 255) / 256, 256, 0, stream>>>(esrc, edst, ew, cursor, perm2, n_edges);
        gather_kernel<<<((size_t)n_nodes * 64 + 255) / 256, 256, 0, stream>>>(h, offsets, perm2, out, n_nodes);
    } else {
        hipMemsetAsync(d_out, 0, (size_t)out_size * sizeof(float), stream);
        scatter_kernel<<<8192, 256, 0, stream>>>(h, esrc, edst, ew, out, n_edges);
    }
}